// Round 14
// baseline (3416.669 us; speedup 1.0000x reference)
//
#include <hip/hip_runtime.h>
#include <cstddef>
#include <cstdint>

#define NB 64
#define NS 512
#define NE 256
#define NH 1024
#define NH3 3072
#define NV 32000

typedef unsigned short u16;
typedef unsigned int u32;
typedef unsigned long long u64;
typedef __attribute__((ext_vector_type(8))) short short8v;
typedef __attribute__((ext_vector_type(4))) float f32x4;
typedef __attribute__((ext_vector_type(4))) unsigned int u32x4;

__device__ __forceinline__ u16 f2bf(float x) {
    u32 u = __float_as_uint(x);
    u32 r = (u + 0x7FFFu + ((u >> 16) & 1u)) >> 16;   // RNE
    return (u16)r;
}
__device__ __forceinline__ float bf2f(u16 h) { return __uint_as_float(((u32)h) << 16); }

#define MFMA16(a, b, c) __builtin_amdgcn_mfma_f32_16x16x32_bf16((a), (b), (c), 0, 0, 0)
#define PIN5(a) asm volatile("" : "+v"(a[0]), "+v"(a[1]), "+v"(a[2]), "+v"(a[3]), "+v"(a[4]))

// issue-only 32B L3-coherent load pair (sc0 sc1), NO waitcnt — caller waits.
#define LD32_ISSUE(a, b, p) \
    asm volatile("global_load_dwordx4 %0, %2, off sc0 sc1\n\t" \
                 "global_load_dwordx4 %1, %2, off offset:16 sc0 sc1" \
                 : "=&v"(a), "=&v"(b) : "v"(p) : "memory")

// ============================================================================
// Packed B layout: [g:64][slot:120][lane:64][j:8] bf16 (hi and lo arrays).
//   slots 0..39: z kc=slot | 40..79: r kc=slot-40 | 80..87: xh kc=slot-48 | 88..119: rh kc=slot-88
// K-concat: k in [0,1024) = h (Uk), [1024,1280) = x (Wk).
// Fragment (16x16x32): lane l -> row/col = l&15, k = (l>>4)*8 + j.
// ============================================================================
__global__ __launch_bounds__(256) void pack_uk(const float* __restrict__ Wk,
                                               const float* __restrict__ Uk,
                                               u16* __restrict__ Bh, u16* __restrict__ Bl) {
    const int idx = blockIdx.x * 256 + threadIdx.x;   // 64*120*512 total
    const int j = idx & 7;
    const int lane = (idx >> 3) & 63;
    const int slot = (idx >> 9) % 120;
    const int g = idx / (120 * 512);
    int tile, kc;
    if (slot < 40) { tile = 0; kc = slot; }
    else if (slot < 80) { tile = 1; kc = slot - 40; }
    else if (slot < 88) { tile = 2; kc = slot - 48; }
    else { tile = 3; kc = slot - 88; }
    const int k = kc * 32 + ((lane >> 4) << 3) + j;
    const int uu = g * 16 + (lane & 15);
    const int col = (tile == 0) ? uu : (tile == 1) ? (NH + uu) : (2 * NH + uu);
    const float v = (k < NH) ? Uk[(size_t)k * NH3 + col]
                             : Wk[(size_t)(k - NH) * NH3 + col];
    const u16 hi = f2bf(v);
    Bh[idx] = hi;
    Bl[idx] = f2bf(v - bf2f(hi));
}

// X fragments for all steps: [s:512][mg:4][kcx:8][lane:64][j:8] bf16 hi/lo
__global__ __launch_bounds__(256) void pack_x(const int* __restrict__ tokens,
                                              const float* __restrict__ emb,
                                              u16* __restrict__ Xh, u16* __restrict__ Xl) {
    const int idx = blockIdx.x * 256 + threadIdx.x;   // 512*4*8*512 total
    const int j = idx & 7;
    const int lane = (idx >> 3) & 63;
    const int kcx = (idx >> 9) & 7;
    const int mg = (idx >> 12) & 3;
    const int s = idx >> 14;
    const int b = mg * 16 + (lane & 15);
    const int e = kcx * 32 + ((lane >> 4) << 3) + j;
    const int tok = tokens[b * NS + s];
    const float v = emb[(size_t)tok * NE + e];
    const u16 hi = f2bf(v);
    Xh[idx] = hi;
    Xl[idx] = f2bf(v - bf2f(hi));
}

// ============================================================================
// Persistent scan, TAGGED DATAFLOW (R12 protocol) + BURST-RETRY SPIN:
// spin loop body = burst-issue ALL 4 fragments' loads (8x dwordx4, no
// intermediate waits) -> single vmcnt(0) -> check all 4 tags -> break/sleep.
// Each retry costs one L3 RTT for everything (vs R12's serial per-fragment
// spins = up to 4 RTTs). x-part MFMAs overlap the first burst's flight.
// State word u32 = hi | ((lo & 0xFFFE | wtag) << 16); WTAG(s)=((s>>1)&1)^1.
// ============================================================================
__global__ __launch_bounds__(512, 2) void gru_scan(
    const int* __restrict__ tokens,
    const u16* __restrict__ Bh, const u16* __restrict__ Bl,
    const u16* __restrict__ Xh, const u16* __restrict__ Xl,
    const float* __restrict__ bias,
    float* __restrict__ hA,
    u32* __restrict__ sA, u32* __restrict__ sB)
{
    __shared__ f32x4 red[8][4][64];   // 32 KB
    __shared__ f32x4 preS[4][64];     // 4 KB

    const int g = blockIdx.x & 63;
    const int mg = blockIdx.x >> 6;
    const int tid = threadIdx.x;
    const int w = tid >> 6;
    const int lane = tid & 63;
    const size_t laneo = (size_t)lane * 8;
    const size_t bbase = (size_t)g * 120 * 512;

    // ---- preload B fragments (held in regs/AGPRs for all 512 steps) ----
    short8v Bz_h[5], Bz_l[5], Br_h[5], Br_l[5], B3_h[5], B3_l[5];
#pragma unroll
    for (int t = 0; t < 5; ++t) {
        const int kc = w + 8 * t;
        const size_t oz = bbase + (size_t)kc * 512 + laneo;
        const size_t orr = bbase + (size_t)(40 + kc) * 512 + laneo;
        const size_t o3 = bbase + (size_t)((t < 4) ? (88 + kc) : (48 + kc)) * 512 + laneo;
        Bz_h[t] = *(const short8v*)(Bh + oz);
        Bz_l[t] = *(const short8v*)(Bl + oz);
        Br_h[t] = *(const short8v*)(Bh + orr);
        Br_l[t] = *(const short8v*)(Bl + orr);
        B3_h[t] = *(const short8v*)(Bh + o3);
        B3_l[t] = *(const short8v*)(Bl + o3);
    }

    // ---- per-fragment state offsets (u32 units) ----
    size_t soff[4];
#pragma unroll
    for (int t = 0; t < 4; ++t)
        soff[t] = (((size_t)(mg * 32 + (w + 8 * t))) << 9) + laneo;

    // ---- gate-thread constants (valid for tid < 256) ----
    const int ll = tid & 63;
    const int q = tid >> 6;
    const int u = g * 16 + (ll & 15);
    const int brow = ((ll >> 4) << 2) + (q & 3);
    const int b = mg * 16 + brow;
    const float bz = bias[u] + bias[NH3 + u];
    const float br = bias[NH + u] + bias[NH3 + NH + u];
    const float bxh = bias[2 * NH + u];
    const float brh = bias[NH3 + 2 * NH + u];
    const size_t hoff = (size_t)b * NH + u;
    const size_t soA = (((size_t)mg * 32 + (u >> 5)) * 64 +
                        (brow + (((u & 31) >> 3) << 4))) * 8 + (u & 7);
    const int* tokp = tokens + b * NS;
    float hp = 0.0f;

    for (int s = 0; s < NS; ++s) {
        const u32* scur = (s & 1) ? sB : sA;
        u32* snext = (s & 1) ? sA : sB;
        const u32 wtag = (((u32)(s >> 1) & 1u) ^ 1u);
        const u32 rtag = (s == 0) ? 0u : ((((u32)(s - 1) >> 1) & 1u) ^ 1u);

        // ---- prefetch x fragment + token (ready data) ----
        const size_t xoff = ((((size_t)s * 4 + mg) * 8 + w) * 64) * 8 + laneo;
        const short8v XAh = *(const short8v*)(Xh + xoff);
        const short8v XAl = *(const short8v*)(Xl + xoff);
        const bool m = tokp[s] != 0;

        // pin B in registers (defeat remat across syncs)
        PIN5(Bz_h); PIN5(Bz_l); PIN5(Br_h); PIN5(Br_l); PIN5(B3_h); PIN5(B3_l);

        // ---- first burst: all 4 fragments (8 loads, no waits between) ----
        u32x4 qa[4], qb[4];
        LD32_ISSUE(qa[0], qb[0], scur + soff[0]);
        LD32_ISSUE(qa[1], qb[1], scur + soff[1]);
        LD32_ISSUE(qa[2], qb[2], scur + soff[2]);
        LD32_ISSUE(qa[3], qb[3], scur + soff[3]);

        f32x4 az0 = {0.f, 0.f, 0.f, 0.f};
        f32x4 az1 = az0, ar0 = az0, ar1 = az0, ah0 = az0, ah1 = az0, axh = az0;

        // ---- x-part MFMAs while the burst flies ----
        az1 = MFMA16(XAh, Bz_h[4], az1);
        ar1 = MFMA16(XAh, Br_h[4], ar1);
        axh = MFMA16(XAh, B3_h[4], axh);
        axh = MFMA16(XAl, B3_h[4], axh);
        axh = MFMA16(XAh, B3_l[4], axh);
        az1 = MFMA16(XAl, Bz_h[4], az1);
        az1 = MFMA16(XAh, Bz_l[4], az1);
        ar1 = MFMA16(XAl, Br_h[4], ar1);
        ar1 = MFMA16(XAh, Br_l[4], ar1);

        // ---- burst-retry spin: one RTT per iteration for ALL fragments ----
        for (;;) {
            asm volatile("s_waitcnt vmcnt(0)" ::: "memory");
            __builtin_amdgcn_sched_barrier(0);   // rule #18
            u32 c[4];
#pragma unroll
            for (int t = 0; t < 4; ++t) {
                const u32 ta = qa[t].x & qa[t].y & qa[t].z & qa[t].w
                             & qb[t].x & qb[t].y & qb[t].z & qb[t].w;
                const u32 to = qa[t].x | qa[t].y | qa[t].z | qa[t].w
                             | qb[t].x | qb[t].y | qb[t].z | qb[t].w;
                c[t] = rtag ? ta : ~to;
            }
            const u32 call = c[0] & c[1] & c[2] & c[3];
            if (__all((int)((call >> 16) & 1u))) break;
            __builtin_amdgcn_s_sleep(1);
            LD32_ISSUE(qa[0], qb[0], scur + soff[0]);
            LD32_ISSUE(qa[1], qb[1], scur + soff[1]);
            LD32_ISSUE(qa[2], qb[2], scur + soff[2]);
            LD32_ISSUE(qa[3], qb[3], scur + soff[3]);
        }

        // ---- unpack + MFMA (2-way split chains), no waits ----
#pragma unroll
        for (int t = 0; t < 4; ++t) {
            union { u32 uw[4]; short8v v; } Ahv, Alv;
            Ahv.uw[0] = (qa[t].x & 0xffffu) | (qa[t].y << 16);
            Ahv.uw[1] = (qa[t].z & 0xffffu) | (qa[t].w << 16);
            Ahv.uw[2] = (qb[t].x & 0xffffu) | (qb[t].y << 16);
            Ahv.uw[3] = (qb[t].z & 0xffffu) | (qb[t].w << 16);
            Alv.uw[0] = ((qa[t].x >> 16) | (qa[t].y & 0xffff0000u)) & 0xFFFEFFFEu;
            Alv.uw[1] = ((qa[t].z >> 16) | (qa[t].w & 0xffff0000u)) & 0xFFFEFFFEu;
            Alv.uw[2] = ((qb[t].x >> 16) | (qb[t].y & 0xffff0000u)) & 0xFFFEFFFEu;
            Alv.uw[3] = ((qb[t].z >> 16) | (qb[t].w & 0xffff0000u)) & 0xFFFEFFFEu;
            const short8v Ah = Ahv.v, Al = Alv.v;
            if (t & 1) {
                az1 = MFMA16(Ah, Bz_h[t], az1);
                ar1 = MFMA16(Ah, Br_h[t], ar1);
                ah1 = MFMA16(Ah, B3_h[t], ah1);
                ah1 = MFMA16(Al, B3_h[t], ah1);
                ah1 = MFMA16(Ah, B3_l[t], ah1);
                az1 = MFMA16(Al, Bz_h[t], az1);
                az1 = MFMA16(Ah, Bz_l[t], az1);
                ar1 = MFMA16(Al, Br_h[t], ar1);
                ar1 = MFMA16(Ah, Br_l[t], ar1);
            } else {
                az0 = MFMA16(Ah, Bz_h[t], az0);
                ar0 = MFMA16(Ah, Br_h[t], ar0);
                ah0 = MFMA16(Ah, B3_h[t], ah0);
                ah0 = MFMA16(Al, B3_h[t], ah0);
                ah0 = MFMA16(Ah, B3_l[t], ah0);
                az0 = MFMA16(Al, Bz_h[t], az0);
                az0 = MFMA16(Ah, Bz_l[t], az0);
                ar0 = MFMA16(Al, Br_h[t], ar0);
                ar0 = MFMA16(Ah, Br_l[t], ar0);
            }
        }

        red[w][0][lane] = az0 + az1;
        red[w][1][lane] = ar0 + ar1;
        red[w][2][lane] = axh;
        red[w][3][lane] = ah0 + ah1;
        __syncthreads();                          // #1: all red written

        if (tid < 256) {
            f32x4 sum = red[0][q][ll];
#pragma unroll
            for (int w2 = 1; w2 < 8; ++w2) {
                const f32x4 v = red[w2][q][ll];
                sum.x += v.x; sum.y += v.y; sum.z += v.z; sum.w += v.w;
            }
            preS[q][ll] = sum;
        }
        __syncthreads();                          // #2: preS ready

        if (tid < 256) {
            const float pz = ((const float*)&preS[0][ll])[q];
            const float pr = ((const float*)&preS[1][ll])[q];
            const float pxh = ((const float*)&preS[2][ll])[q];
            const float prh = ((const float*)&preS[3][ll])[q];
            const float z = 1.0f / (1.0f + __expf(-(pz + bz)));
            const float r = 1.0f / (1.0f + __expf(-(pr + br)));
            const float xx = pxh + bxh + r * (prh + brh);
            const float e2 = __expf(-2.0f * xx);
            const float hh = (1.0f - e2) / (1.0f + e2);
            const float hnv = m ? (z * hp + (1.0f - z) * hh) : hp;
            hp = hnv;
            if (s < NS - 1) {
                const u16 hi = f2bf(hnv);
                const u16 lo = f2bf(hnv - bf2f(hi));
                const u32 word = (u32)hi | ((((u32)lo & 0xFFFEu) | wtag) << 16);
                __hip_atomic_store(snext + soA, word,
                                   __ATOMIC_RELAXED, __HIP_MEMORY_SCOPE_AGENT);
            }
        }
        // no post-gate barrier: tags carry readiness.
    }

    if (tid < 256) hA[hoff] = hp;   // final h for out_mm
}

// ---------------- out = h[64,1024] @ Wout[1024,32000] ----------------
__global__ __launch_bounds__(256) void out_mm2(const float* __restrict__ h,
                                               const float* __restrict__ Wout,
                                               float* __restrict__ out) {
    __shared__ float red[4][NB][64];   // 64 KB
    const int cl = threadIdx.x & 63;
    const int ks = threadIdx.x >> 6;
    const int col = blockIdx.x * 64 + cl;
    float acc[NB];
#pragma unroll
    for (int b = 0; b < NB; ++b) acc[b] = 0.0f;
    const int k0 = ks * 256;
    for (int k = k0; k < k0 + 256; ++k) {
        const float wv = Wout[(size_t)k * NV + col];
#pragma unroll
        for (int b = 0; b < NB; ++b) acc[b] = fmaf(h[b * NH + k], wv, acc[b]);
    }
#pragma unroll
    for (int b = 0; b < NB; ++b) red[ks][b][cl] = acc[b];
    __syncthreads();
    for (int i = threadIdx.x; i < NB * 64; i += 256) {
        const int b = i >> 6;
        const int c2 = i & 63;
        const float v = red[0][b][c2] + red[1][b][c2] + red[2][b][c2] + red[3][b][c2];
        out[(size_t)b * NV + blockIdx.x * 64 + c2] = v;
    }
}

// ============================================================================
// Fallback (fp32, small-ws) — R2 path
// ============================================================================
#define NBT 8
#define UT 16
#define KS 16
#define KH (NH / KS)
#define KX (NE / KS)
__device__ __forceinline__ int hrow(int k) { return k + (k >> 6); }
__device__ __forceinline__ int xrow(int k) { return k + (k >> 4); }

__global__ __launch_bounds__(256) void gru_step2(
    const int* __restrict__ tokens, const float* __restrict__ emb,
    const float* __restrict__ Wk, const float* __restrict__ Uk,
    const float* __restrict__ bias,
    const float* __restrict__ h_in, float* __restrict__ h_out, int s)
{
    __shared__ float hs[NH + NH / 64][NBT];
    __shared__ float xs[NE + NE / 16][NBT];
    __shared__ float red[4][NBT][256];
    const int tid = threadIdx.x;
    const int ug = blockIdx.x & 63;
    const int bg = blockIdx.x >> 6;
    for (int i = tid; i < NBT * (NE / 4); i += 256) {
        const int bl = i >> 6; const int e4 = i & 63;
        const int b = bg * NBT + bl;
        const int tok = tokens[b * NS + s];
        const float4 v = ((const float4*)(emb + (size_t)tok * NE))[e4];
        const int k0 = e4 * 4;
        xs[xrow(k0 + 0)][bl] = v.x; xs[xrow(k0 + 1)][bl] = v.y;
        xs[xrow(k0 + 2)][bl] = v.z; xs[xrow(k0 + 3)][bl] = v.w;
    }
    for (int i = tid; i < NBT * (NH / 4); i += 256) {
        const int bl = i >> 8; const int k4 = i & 255;
        const int b = bg * NBT + bl;
        const float4 v = ((const float4*)(h_in + (size_t)b * NH))[k4];
        const int r = hrow(k4 * 4);
        hs[r + 0][bl] = v.x; hs[r + 1][bl] = v.y; hs[r + 2][bl] = v.z; hs[r + 3][bl] = v.w;
    }
    __syncthreads();
    const int ul = tid & 15;
    const int ks = tid >> 4;
    const int u = ug * UT + ul;
    float az[NBT], ar[NBT], axh[NBT], arh[NBT];
#pragma unroll
    for (int b = 0; b < NBT; ++b) { az[b] = 0.f; ar[b] = 0.f; axh[b] = 0.f; arh[b] = 0.f; }
    {
        size_t off = (size_t)(ks * KH) * NH3 + u;
        const int r0 = ks * (KH + 1);
#pragma unroll 4
        for (int kk = 0; kk < KH; ++kk) {
            const float uz = Uk[off], ur = Uk[off + NH], uh = Uk[off + 2 * NH];
            float hv[8];
            *(float4*)&hv[0] = *(const float4*)&hs[r0 + kk][0];
            *(float4*)&hv[4] = *(const float4*)&hs[r0 + kk][4];
#pragma unroll
            for (int b = 0; b < NBT; ++b) {
                az[b] = fmaf(hv[b], uz, az[b]); ar[b] = fmaf(hv[b], ur, ar[b]);
                arh[b] = fmaf(hv[b], uh, arh[b]);
            }
            off += NH3;
        }
    }
    {
        size_t off = (size_t)(ks * KX) * NH3 + u;
        const int r0 = ks * (KX + 1);
#pragma unroll 4
        for (int kk = 0; kk < KX; ++kk) {
            const float wz = Wk[off], wr = Wk[off + NH], wh = Wk[off + 2 * NH];
            float xv[8];
            *(float4*)&xv[0] = *(const float4*)&xs[r0 + kk][0];
            *(float4*)&xv[4] = *(const float4*)&xs[r0 + kk][4];
#pragma unroll
            for (int b = 0; b < NBT; ++b) {
                az[b] = fmaf(xv[b], wz, az[b]); ar[b] = fmaf(xv[b], wr, ar[b]);
                axh[b] = fmaf(xv[b], wh, axh[b]);
            }
            off += NH3;
        }
    }
#pragma unroll
    for (int b = 0; b < NBT; ++b) {
        red[0][b][tid] = az[b]; red[1][b][tid] = ar[b];
        red[2][b][tid] = axh[b]; red[3][b][tid] = arh[b];
    }
    __syncthreads();
    if (tid < 128) {
        const int ul2 = tid & 15;
        const int bl = tid >> 4;
        const int u2 = ug * UT + ul2;
        const int b = bg * NBT + bl;
        float sz = 0.f, sr = 0.f, sxh = 0.f, srh = 0.f;
#pragma unroll
        for (int k2 = 0; k2 < KS; ++k2) {
            const int t2 = k2 * 16 + ul2;
            sz += red[0][bl][t2]; sr += red[1][bl][t2];
            sxh += red[2][bl][t2]; srh += red[3][bl][t2];
        }
        sz += bias[u2] + bias[NH3 + u2];
        sr += bias[NH + u2] + bias[NH3 + NH + u2];
        sxh += bias[2 * NH + u2];
        srh += bias[NH3 + 2 * NH + u2];
        const float z = 1.0f / (1.0f + expf(-sz));
        const float r = 1.0f / (1.0f + expf(-sr));
        const float hh = tanhf(sxh + r * srh);
        const float hp = hs[hrow(u2)][bl];
        const bool m = tokens[b * NS + s] != 0;
        h_out[(size_t)b * NH + u2] = m ? (z * hp + (1.0f - z) * hh) : hp;
    }
}

extern "C" void kernel_launch(void* const* d_in, const int* in_sizes, int n_in,
                              void* d_out, int out_size, void* d_ws, size_t ws_size,
                              hipStream_t stream) {
    const int* tokens = (const int*)d_in[0];
    const float* emb = (const float*)d_in[1];
    const float* Wk = (const float*)d_in[2];
    const float* Uk = (const float*)d_in[3];
    const float* bias = (const float*)d_in[4];
    const float* Wout = (const float*)d_in[5];
    float* out = (float*)d_out;

    const size_t B_ELEMS = (size_t)64 * 120 * 512;   // 3,932,160
    const size_t X_ELEMS = (size_t)NS * 4 * 8 * 512; // 8,388,608
    const size_t H_ELEMS = (size_t)NB * NH;          // 65,536
    const size_t HS_ELEMS = (size_t)4 * 32 * 64 * 8; // 65,536 (u32 combined+tag)

    size_t off = 0;
    auto take = [&](size_t bytes) { size_t o = off; off += (bytes + 255) & ~255ULL; return o; };
    const size_t oBh = take(B_ELEMS * 2), oBl = take(B_ELEMS * 2);
    const size_t oXh = take(X_ELEMS * 2), oXl = take(X_ELEMS * 2);
    const size_t ohA = take(H_ELEMS * 4);
    const size_t osA = take(HS_ELEMS * 4), osB = take(HS_ELEMS * 4);

    char* base = (char*)d_ws;

    if (off <= ws_size) {
        u16* Bh = (u16*)(base + oBh); u16* Bl = (u16*)(base + oBl);
        u16* Xh = (u16*)(base + oXh); u16* Xl = (u16*)(base + oXl);
        float* hA = (float*)(base + ohA);
        u32* sA = (u32*)(base + osA); u32* sB = (u32*)(base + osB);

        // both state buffers -> tag 0 (first real write uses tag 1)
        hipMemsetAsync(sA, 0, HS_ELEMS * 4, stream);
        hipMemsetAsync(sB, 0, HS_ELEMS * 4, stream);
        pack_uk<<<(int)(B_ELEMS / 256), 256, 0, stream>>>(Wk, Uk, Bh, Bl);
        pack_x<<<(int)(X_ELEMS / 256), 256, 0, stream>>>(tokens, emb, Xh, Xl);

        gru_scan<<<256, 512, 0, stream>>>(tokens, Bh, Bl, Xh, Xl, bias,
                                          hA, sA, sB);
        out_mm2<<<500, 256, 0, stream>>>(hA, Wout, out);
    } else {
        float* h0 = (float*)d_ws;
        float* h1 = h0 + H_ELEMS;
        hipMemsetAsync(h0, 0, H_ELEMS * 4, stream);
        for (int s = 0; s < NS; ++s) {
            const float* hin = (s & 1) ? h1 : h0;
            float* hout = (s & 1) ? h0 : h1;
            gru_step2<<<512, 256, 0, stream>>>(tokens, emb, Wk, Uk, bias, hin, hout, s);
        }
        out_mm2<<<500, 256, 0, stream>>>(h0, Wout, out);
    }
}

// Round 15
// 2310.453 us; speedup vs baseline: 1.4788x; 1.4788x over previous
//
#include <hip/hip_runtime.h>
#include <cstddef>
#include <cstdint>

#define NB 64
#define NS 512
#define NE 256
#define NH 1024
#define NH3 3072
#define NV 32000

typedef unsigned short u16;
typedef unsigned int u32;
typedef unsigned long long u64;
typedef __attribute__((ext_vector_type(8))) short short8v;
typedef __attribute__((ext_vector_type(4))) float f32x4;
typedef __attribute__((ext_vector_type(4))) unsigned int u32x4;

__device__ __forceinline__ u16 f2bf(float x) {
    u32 u = __float_as_uint(x);
    u32 r = (u + 0x7FFFu + ((u >> 16) & 1u)) >> 16;   // RNE
    return (u16)r;
}
__device__ __forceinline__ float bf2f(u16 h) { return __uint_as_float(((u32)h) << 16); }

#define MFMA16(a, b, c) __builtin_amdgcn_mfma_f32_16x16x32_bf16((a), (b), (c), 0, 0, 0)
#define PIN5(a) asm volatile("" : "+v"(a[0]), "+v"(a[1]), "+v"(a[2]), "+v"(a[3]), "+v"(a[4]))

// blocking 32B L3-coherent load (sc0 sc1: bypass L1+L2, read coherence point)
#define LD32(a, b, p) \
    asm volatile("global_load_dwordx4 %0, %2, off sc0 sc1\n\t" \
                 "global_load_dwordx4 %1, %2, off offset:16 sc0 sc1\n\t" \
                 "s_waitcnt vmcnt(0)" \
                 : "=&v"(a), "=&v"(b) : "v"(p) : "memory")

// ============================================================================
// Packed B layout: [g:64][slot:120][lane:64][j:8] bf16 (hi and lo arrays).
//   slots 0..39: z kc=slot | 40..79: r kc=slot-40 | 80..87: xh kc=slot-48 | 88..119: rh kc=slot-88
// K-concat: k in [0,1024) = h (Uk), [1024,1280) = x (Wk).
// Fragment (16x16x32): lane l -> row/col = l&15, k = (l>>4)*8 + j.
// ============================================================================
__global__ __launch_bounds__(256) void pack_uk(const float* __restrict__ Wk,
                                               const float* __restrict__ Uk,
                                               u16* __restrict__ Bh, u16* __restrict__ Bl) {
    const int idx = blockIdx.x * 256 + threadIdx.x;   // 64*120*512 total
    const int j = idx & 7;
    const int lane = (idx >> 3) & 63;
    const int slot = (idx >> 9) % 120;
    const int g = idx / (120 * 512);
    int tile, kc;
    if (slot < 40) { tile = 0; kc = slot; }
    else if (slot < 80) { tile = 1; kc = slot - 40; }
    else if (slot < 88) { tile = 2; kc = slot - 48; }
    else { tile = 3; kc = slot - 88; }
    const int k = kc * 32 + ((lane >> 4) << 3) + j;
    const int uu = g * 16 + (lane & 15);
    const int col = (tile == 0) ? uu : (tile == 1) ? (NH + uu) : (2 * NH + uu);
    const float v = (k < NH) ? Uk[(size_t)k * NH3 + col]
                             : Wk[(size_t)(k - NH) * NH3 + col];
    const u16 hi = f2bf(v);
    Bh[idx] = hi;
    Bl[idx] = f2bf(v - bf2f(hi));
}

// X fragments for all steps: [s:512][mg:4][kcx:8][lane:64][j:8] bf16 hi/lo
__global__ __launch_bounds__(256) void pack_x(const int* __restrict__ tokens,
                                              const float* __restrict__ emb,
                                              u16* __restrict__ Xh, u16* __restrict__ Xl) {
    const int idx = blockIdx.x * 256 + threadIdx.x;   // 512*4*8*512 total
    const int j = idx & 7;
    const int lane = (idx >> 3) & 63;
    const int kcx = (idx >> 9) & 7;
    const int mg = (idx >> 12) & 3;
    const int s = idx >> 14;
    const int b = mg * 16 + (lane & 15);
    const int e = kcx * 32 + ((lane >> 4) << 3) + j;
    const int tok = tokens[b * NS + s];
    const float v = emb[(size_t)tok * NE + e];
    const u16 hi = f2bf(v);
    Xh[idx] = hi;
    Xl[idx] = f2bf(v - bf2f(hi));
}

// ============================================================================
// Persistent scan with TAGGED DATAFLOW (no barriers, no flags, no counters).
// 256 blocks = mg(4) x g(64). 512 thr = 8 waves. B pinned in regs/AGPRs.
// State word u32 = hi | ((lo & 0xFFFE | wtag) << 16): bit16 = generation tag.
//   WTAG(s) = ((s>>1)&1)^1 alternates per reuse of each ping-pong buffer;
//   consumer at step s spins until all 8 words of its fragment carry
//   WTAG(s-1). Serial per-fragment spins are the measured optimum (R12):
//   they rate-limit L3 poll traffic, and fragments t+1.. are ready by the
//   time their spin starts, costing ~1 RTT each with MFMA interleaved.
//   (R13 early-burst and R14 burst-retry both regressed ~50%.)
// ============================================================================
__global__ __launch_bounds__(512, 2) void gru_scan(
    const int* __restrict__ tokens,
    const u16* __restrict__ Bh, const u16* __restrict__ Bl,
    const u16* __restrict__ Xh, const u16* __restrict__ Xl,
    const float* __restrict__ bias,
    float* __restrict__ hA,
    u32* __restrict__ sA, u32* __restrict__ sB)
{
    __shared__ f32x4 red[8][4][64];   // 32 KB
    __shared__ f32x4 preS[4][64];     // 4 KB

    const int g = blockIdx.x & 63;
    const int mg = blockIdx.x >> 6;
    const int tid = threadIdx.x;
    const int w = tid >> 6;
    const int lane = tid & 63;
    const size_t laneo = (size_t)lane * 8;
    const size_t bbase = (size_t)g * 120 * 512;

    // ---- preload B fragments (held in regs/AGPRs for all 512 steps) ----
    short8v Bz_h[5], Bz_l[5], Br_h[5], Br_l[5], B3_h[5], B3_l[5];
#pragma unroll
    for (int t = 0; t < 5; ++t) {
        const int kc = w + 8 * t;
        const size_t oz = bbase + (size_t)kc * 512 + laneo;
        const size_t orr = bbase + (size_t)(40 + kc) * 512 + laneo;
        const size_t o3 = bbase + (size_t)((t < 4) ? (88 + kc) : (48 + kc)) * 512 + laneo;
        Bz_h[t] = *(const short8v*)(Bh + oz);
        Bz_l[t] = *(const short8v*)(Bl + oz);
        Br_h[t] = *(const short8v*)(Bh + orr);
        Br_l[t] = *(const short8v*)(Bl + orr);
        B3_h[t] = *(const short8v*)(Bh + o3);
        B3_l[t] = *(const short8v*)(Bl + o3);
    }

    // ---- gate-thread constants (valid for tid < 256) ----
    const int ll = tid & 63;
    const int q = tid >> 6;
    const int u = g * 16 + (ll & 15);
    const int brow = ((ll >> 4) << 2) + (q & 3);
    const int b = mg * 16 + brow;
    const float bz = bias[u] + bias[NH3 + u];
    const float br = bias[NH + u] + bias[NH3 + NH + u];
    const float bxh = bias[2 * NH + u];
    const float brh = bias[NH3 + 2 * NH + u];
    const size_t hoff = (size_t)b * NH + u;
    const size_t soA = (((size_t)mg * 32 + (u >> 5)) * 64 +
                        (brow + (((u & 31) >> 3) << 4))) * 8 + (u & 7);
    const int* tokp = tokens + b * NS;
    float hp = 0.0f;

    for (int s = 0; s < NS; ++s) {
        const u32* scur = (s & 1) ? sB : sA;
        u32* snext = (s & 1) ? sA : sB;
        const u32 wtag = (((u32)(s >> 1) & 1u) ^ 1u);
        const u32 rtag = (s == 0) ? 0u : ((((u32)(s - 1) >> 1) & 1u) ^ 1u);

        // ---- prefetch x fragment + token (ready data, overlaps first spin) ----
        const size_t xoff = ((((size_t)s * 4 + mg) * 8 + w) * 64) * 8 + laneo;
        const short8v XAh = *(const short8v*)(Xh + xoff);
        const short8v XAl = *(const short8v*)(Xl + xoff);
        const bool m = tokp[s] != 0;

        // pin B in registers (defeat remat across syncs)
        PIN5(Bz_h); PIN5(Bz_l); PIN5(Br_h); PIN5(Br_l); PIN5(B3_h); PIN5(B3_l);

        f32x4 az0 = {0.f, 0.f, 0.f, 0.f};
        f32x4 az1 = az0, ar0 = az0, ar1 = az0, ah0 = az0, ah1 = az0, axh = az0;

        // ---- x-part MFMAs first (inputs in regs; overlap h-state arrival) ----
        az1 = MFMA16(XAh, Bz_h[4], az1);
        ar1 = MFMA16(XAh, Br_h[4], ar1);
        axh = MFMA16(XAh, B3_h[4], axh);
        axh = MFMA16(XAl, B3_h[4], axh);
        axh = MFMA16(XAh, B3_l[4], axh);
        az1 = MFMA16(XAl, Bz_h[4], az1);
        az1 = MFMA16(XAh, Bz_l[4], az1);
        ar1 = MFMA16(XAl, Br_h[4], ar1);
        ar1 = MFMA16(XAh, Br_l[4], ar1);

        // ---- h-part: per-fragment tag-spin, unpack, MFMA (split chains) ----
#pragma unroll
        for (int t = 0; t < 4; ++t) {
            const int kc = w + 8 * t;
            const u32* p = scur + (((size_t)(mg * 32 + kc)) << 9) + laneo;
            u32x4 qa, qb;
            for (;;) {
                LD32(qa, qb, p);
                const u32 ta = qa.x & qa.y & qa.z & qa.w & qb.x & qb.y & qb.z & qb.w;
                const u32 to = qa.x | qa.y | qa.z | qa.w | qb.x | qb.y | qb.z | qb.w;
                const u32 chk = rtag ? ta : ~to;
                if (__all((int)((chk >> 16) & 1u))) break;
                __builtin_amdgcn_s_sleep(1);
            }
            union { u32 uw[4]; short8v v; } Ahv, Alv;
            Ahv.uw[0] = (qa.x & 0xffffu) | (qa.y << 16);
            Ahv.uw[1] = (qa.z & 0xffffu) | (qa.w << 16);
            Ahv.uw[2] = (qb.x & 0xffffu) | (qb.y << 16);
            Ahv.uw[3] = (qb.z & 0xffffu) | (qb.w << 16);
            Alv.uw[0] = ((qa.x >> 16) | (qa.y & 0xffff0000u)) & 0xFFFEFFFEu;
            Alv.uw[1] = ((qa.z >> 16) | (qa.w & 0xffff0000u)) & 0xFFFEFFFEu;
            Alv.uw[2] = ((qb.x >> 16) | (qb.y & 0xffff0000u)) & 0xFFFEFFFEu;
            Alv.uw[3] = ((qb.z >> 16) | (qb.w & 0xffff0000u)) & 0xFFFEFFFEu;
            const short8v Ah = Ahv.v, Al = Alv.v;
            if (t & 1) {
                az1 = MFMA16(Ah, Bz_h[t], az1);
                ar1 = MFMA16(Ah, Br_h[t], ar1);
                ah1 = MFMA16(Ah, B3_h[t], ah1);
                ah1 = MFMA16(Al, B3_h[t], ah1);
                ah1 = MFMA16(Ah, B3_l[t], ah1);
                az1 = MFMA16(Al, Bz_h[t], az1);
                az1 = MFMA16(Ah, Bz_l[t], az1);
                ar1 = MFMA16(Al, Br_h[t], ar1);
                ar1 = MFMA16(Ah, Br_l[t], ar1);
            } else {
                az0 = MFMA16(Ah, Bz_h[t], az0);
                ar0 = MFMA16(Ah, Br_h[t], ar0);
                ah0 = MFMA16(Ah, B3_h[t], ah0);
                ah0 = MFMA16(Al, B3_h[t], ah0);
                ah0 = MFMA16(Ah, B3_l[t], ah0);
                az0 = MFMA16(Al, Bz_h[t], az0);
                az0 = MFMA16(Ah, Bz_l[t], az0);
                ar0 = MFMA16(Al, Br_h[t], ar0);
                ar0 = MFMA16(Ah, Br_l[t], ar0);
            }
        }

        red[w][0][lane] = az0 + az1;
        red[w][1][lane] = ar0 + ar1;
        red[w][2][lane] = axh;
        red[w][3][lane] = ah0 + ah1;
        __syncthreads();                          // #1: all red written

        if (tid < 256) {
            f32x4 sum = red[0][q][ll];
#pragma unroll
            for (int w2 = 1; w2 < 8; ++w2) {
                const f32x4 v = red[w2][q][ll];
                sum.x += v.x; sum.y += v.y; sum.z += v.z; sum.w += v.w;
            }
            preS[q][ll] = sum;
        }
        __syncthreads();                          // #2: preS ready

        if (tid < 256) {
            const float pz = ((const float*)&preS[0][ll])[q];
            const float pr = ((const float*)&preS[1][ll])[q];
            const float pxh = ((const float*)&preS[2][ll])[q];
            const float prh = ((const float*)&preS[3][ll])[q];
            const float z = 1.0f / (1.0f + __expf(-(pz + bz)));
            const float r = 1.0f / (1.0f + __expf(-(pr + br)));
            const float xx = pxh + bxh + r * (prh + brh);
            const float e2 = __expf(-2.0f * xx);
            const float hh = (1.0f - e2) / (1.0f + e2);
            const float hnv = m ? (z * hp + (1.0f - z) * hh) : hp;
            hp = hnv;
            if (s < NS - 1) {
                const u16 hi = f2bf(hnv);
                const u16 lo = f2bf(hnv - bf2f(hi));
                const u32 word = (u32)hi | ((((u32)lo & 0xFFFEu) | wtag) << 16);
                __hip_atomic_store(snext + soA, word,
                                   __ATOMIC_RELAXED, __HIP_MEMORY_SCOPE_AGENT);
            }
        }
        // no post-gate barrier: tags carry readiness; loop back to spin.
    }

    if (tid < 256) hA[hoff] = hp;   // final h for out_mm
}

// ---------------- out = h[64,1024] @ Wout[1024,32000] ----------------
__global__ __launch_bounds__(256) void out_mm2(const float* __restrict__ h,
                                               const float* __restrict__ Wout,
                                               float* __restrict__ out) {
    __shared__ float red[4][NB][64];   // 64 KB
    const int cl = threadIdx.x & 63;
    const int ks = threadIdx.x >> 6;
    const int col = blockIdx.x * 64 + cl;
    float acc[NB];
#pragma unroll
    for (int b = 0; b < NB; ++b) acc[b] = 0.0f;
    const int k0 = ks * 256;
    for (int k = k0; k < k0 + 256; ++k) {
        const float wv = Wout[(size_t)k * NV + col];
#pragma unroll
        for (int b = 0; b < NB; ++b) acc[b] = fmaf(h[b * NH + k], wv, acc[b]);
    }
#pragma unroll
    for (int b = 0; b < NB; ++b) red[ks][b][cl] = acc[b];
    __syncthreads();
    for (int i = threadIdx.x; i < NB * 64; i += 256) {
        const int b = i >> 6;
        const int c2 = i & 63;
        const float v = red[0][b][c2] + red[1][b][c2] + red[2][b][c2] + red[3][b][c2];
        out[(size_t)b * NV + blockIdx.x * 64 + c2] = v;
    }
}

// ============================================================================
// Fallback (fp32, small-ws) — R2 path
// ============================================================================
#define NBT 8
#define UT 16
#define KS 16
#define KH (NH / KS)
#define KX (NE / KS)
__device__ __forceinline__ int hrow(int k) { return k + (k >> 6); }
__device__ __forceinline__ int xrow(int k) { return k + (k >> 4); }

__global__ __launch_bounds__(256) void gru_step2(
    const int* __restrict__ tokens, const float* __restrict__ emb,
    const float* __restrict__ Wk, const float* __restrict__ Uk,
    const float* __restrict__ bias,
    const float* __restrict__ h_in, float* __restrict__ h_out, int s)
{
    __shared__ float hs[NH + NH / 64][NBT];
    __shared__ float xs[NE + NE / 16][NBT];
    __shared__ float red[4][NBT][256];
    const int tid = threadIdx.x;
    const int ug = blockIdx.x & 63;
    const int bg = blockIdx.x >> 6;
    for (int i = tid; i < NBT * (NE / 4); i += 256) {
        const int bl = i >> 6; const int e4 = i & 63;
        const int b = bg * NBT + bl;
        const int tok = tokens[b * NS + s];
        const float4 v = ((const float4*)(emb + (size_t)tok * NE))[e4];
        const int k0 = e4 * 4;
        xs[xrow(k0 + 0)][bl] = v.x; xs[xrow(k0 + 1)][bl] = v.y;
        xs[xrow(k0 + 2)][bl] = v.z; xs[xrow(k0 + 3)][bl] = v.w;
    }
    for (int i = tid; i < NBT * (NH / 4); i += 256) {
        const int bl = i >> 8; const int k4 = i & 255;
        const int b = bg * NBT + bl;
        const float4 v = ((const float4*)(h_in + (size_t)b * NH))[k4];
        const int r = hrow(k4 * 4);
        hs[r + 0][bl] = v.x; hs[r + 1][bl] = v.y; hs[r + 2][bl] = v.z; hs[r + 3][bl] = v.w;
    }
    __syncthreads();
    const int ul = tid & 15;
    const int ks = tid >> 4;
    const int u = ug * UT + ul;
    float az[NBT], ar[NBT], axh[NBT], arh[NBT];
#pragma unroll
    for (int b = 0; b < NBT; ++b) { az[b] = 0.f; ar[b] = 0.f; axh[b] = 0.f; arh[b] = 0.f; }
    {
        size_t off = (size_t)(ks * KH) * NH3 + u;
        const int r0 = ks * (KH + 1);
#pragma unroll 4
        for (int kk = 0; kk < KH; ++kk) {
            const float uz = Uk[off], ur = Uk[off + NH], uh = Uk[off + 2 * NH];
            float hv[8];
            *(float4*)&hv[0] = *(const float4*)&hs[r0 + kk][0];
            *(float4*)&hv[4] = *(const float4*)&hs[r0 + kk][4];
#pragma unroll
            for (int b = 0; b < NBT; ++b) {
                az[b] = fmaf(hv[b], uz, az[b]); ar[b] = fmaf(hv[b], ur, ar[b]);
                arh[b] = fmaf(hv[b], uh, arh[b]);
            }
            off += NH3;
        }
    }
    {
        size_t off = (size_t)(ks * KX) * NH3 + u;
        const int r0 = ks * (KX + 1);
#pragma unroll 4
        for (int kk = 0; kk < KX; ++kk) {
            const float wz = Wk[off], wr = Wk[off + NH], wh = Wk[off + 2 * NH];
            float xv[8];
            *(float4*)&xv[0] = *(const float4*)&xs[r0 + kk][0];
            *(float4*)&xv[4] = *(const float4*)&xs[r0 + kk][4];
#pragma unroll
            for (int b = 0; b < NBT; ++b) {
                az[b] = fmaf(xv[b], wz, az[b]); ar[b] = fmaf(xv[b], wr, ar[b]);
                axh[b] = fmaf(xv[b], wh, axh[b]);
            }
            off += NH3;
        }
    }
#pragma unroll
    for (int b = 0; b < NBT; ++b) {
        red[0][b][tid] = az[b]; red[1][b][tid] = ar[b];
        red[2][b][tid] = axh[b]; red[3][b][tid] = arh[b];
    }
    __syncthreads();
    if (tid < 128) {
        const int ul2 = tid & 15;
        const int bl = tid >> 4;
        const int u2 = ug * UT + ul2;
        const int b = bg * NBT + bl;
        float sz = 0.f, sr = 0.f, sxh = 0.f, srh = 0.f;
#pragma unroll
        for (int k2 = 0; k2 < KS; ++k2) {
            const int t2 = k2 * 16 + ul2;
            sz += red[0][bl][t2]; sr += red[1][bl][t2];
            sxh += red[2][bl][t2]; srh += red[3][bl][t2];
        }
        sz += bias[u2] + bias[NH3 + u2];
        sr += bias[NH + u2] + bias[NH3 + NH + u2];
        sxh += bias[2 * NH + u2];
        srh += bias[NH3 + 2 * NH + u2];
        const float z = 1.0f / (1.0f + expf(-sz));
        const float r = 1.0f / (1.0f + expf(-sr));
        const float hh = tanhf(sxh + r * srh);
        const float hp = hs[hrow(u2)][bl];
        const bool m = tokens[b * NS + s] != 0;
        h_out[(size_t)b * NH + u2] = m ? (z * hp + (1.0f - z) * hh) : hp;
    }
}

extern "C" void kernel_launch(void* const* d_in, const int* in_sizes, int n_in,
                              void* d_out, int out_size, void* d_ws, size_t ws_size,
                              hipStream_t stream) {
    const int* tokens = (const int*)d_in[0];
    const float* emb = (const float*)d_in[1];
    const float* Wk = (const float*)d_in[2];
    const float* Uk = (const float*)d_in[3];
    const float* bias = (const float*)d_in[4];
    const float* Wout = (const float*)d_in[5];
    float* out = (float*)d_out;

    const size_t B_ELEMS = (size_t)64 * 120 * 512;   // 3,932,160
    const size_t X_ELEMS = (size_t)NS * 4 * 8 * 512; // 8,388,608
    const size_t H_ELEMS = (size_t)NB * NH;          // 65,536
    const size_t HS_ELEMS = (size_t)4 * 32 * 64 * 8; // 65,536 (u32 combined+tag)

    size_t off = 0;
    auto take = [&](size_t bytes) { size_t o = off; off += (bytes + 255) & ~255ULL; return o; };
    const size_t oBh = take(B_ELEMS * 2), oBl = take(B_ELEMS * 2);
    const size_t oXh = take(X_ELEMS * 2), oXl = take(X_ELEMS * 2);
    const size_t ohA = take(H_ELEMS * 4);
    const size_t osA = take(HS_ELEMS * 4), osB = take(HS_ELEMS * 4);

    char* base = (char*)d_ws;

    if (off <= ws_size) {
        u16* Bh = (u16*)(base + oBh); u16* Bl = (u16*)(base + oBl);
        u16* Xh = (u16*)(base + oXh); u16* Xl = (u16*)(base + oXl);
        float* hA = (float*)(base + ohA);
        u32* sA = (u32*)(base + osA); u32* sB = (u32*)(base + osB);

        // both state buffers -> tag 0 (first real write uses tag 1)
        hipMemsetAsync(sA, 0, HS_ELEMS * 4, stream);
        hipMemsetAsync(sB, 0, HS_ELEMS * 4, stream);
        pack_uk<<<(int)(B_ELEMS / 256), 256, 0, stream>>>(Wk, Uk, Bh, Bl);
        pack_x<<<(int)(X_ELEMS / 256), 256, 0, stream>>>(tokens, emb, Xh, Xl);

        gru_scan<<<256, 512, 0, stream>>>(tokens, Bh, Bl, Xh, Xl, bias,
                                          hA, sA, sB);
        out_mm2<<<500, 256, 0, stream>>>(hA, Wout, out);
    } else {
        float* h0 = (float*)d_ws;
        float* h1 = h0 + H_ELEMS;
        hipMemsetAsync(h0, 0, H_ELEMS * 4, stream);
        for (int s = 0; s < NS; ++s) {
            const float* hin = (s & 1) ? h1 : h0;
            float* hout = (s & 1) ? h0 : h1;
            gru_step2<<<512, 256, 0, stream>>>(tokens, emb, Wk, Uk, bias, hin, hout, s);
        }
        out_mm2<<<500, 256, 0, stream>>>(h0, Wout, out);
    }
}